// Round 3
// baseline (234.080 us; speedup 1.0000x reference)
//
#include <hip/hip_runtime.h>
#include <hip/hip_bf16.h>
#include <stdint.h>

// Problem constants (DynamicConv1dTBC): T=2048 B=8 C=1024 H=16 K=7 pad_l=6
#define T_DIM 2048
#define B_DIM 8
#define C_DIM 1024
#define H_DIM 16
#define K_DIM 7
#define M_DIM (T_DIM * B_DIM)   // 16384 rows (m = t*B + b)
#define NLOG 144                // H*K (112) + 2H (32) logit columns
#define CW_STRIDE 128           // compact conv-weights row: 112 wk + 16 gates

typedef __attribute__((ext_vector_type(8))) short short8;
typedef __attribute__((ext_vector_type(4))) float floatx4;

__device__ __forceinline__ ushort f2bf(float f) {
    __hip_bfloat16 h = __float2bfloat16(f);
    return *(ushort*)&h;
}

// ---------------------------------------------------------------------------
// Kernel W: fp32 -> bf16 downcast of weights: [w_weight;glu_w] -> wb (144x1024)
// and out_w -> Wb (1024x1024).
// ---------------------------------------------------------------------------
#define S_W  ((size_t)112 * C_DIM)
#define S_G  ((size_t)32 * C_DIM)
#define S_O  ((size_t)C_DIM * C_DIM)
#define S_WG (S_W + S_G)
#define S_CVT (S_WG + S_O)                  // 1,196,032 = 4*256*1168

__global__ __launch_bounds__(256) void cvt_w_kernel(
    const float* __restrict__ w_weight, const float* __restrict__ glu_w,
    const float* __restrict__ out_w,
    ushort* __restrict__ wb, ushort* __restrict__ Wb)
{
    size_t gid = ((size_t)blockIdx.x * 256 + threadIdx.x) * 4;
    const float* src; ushort* dst; size_t off;
    if (gid < S_W)            { src = w_weight; dst = wb;       off = gid; }
    else if (gid < S_WG)      { src = glu_w;    dst = wb + S_W; off = gid - S_W; }
    else                      { src = out_w;    dst = Wb;       off = gid - S_WG; }
    float4 v = *(const float4*)(src + off);
    ushort4 o; o.x = f2bf(v.x); o.y = f2bf(v.y); o.z = f2bf(v.z); o.w = f2bf(v.w);
    *(ushort4*)(dst + off) = o;
}

// ---------------------------------------------------------------------------
// Kernel L: logits GEMM (M=16384, N=144, K=1024) + softmax/gate epilogue.
// m-tile 64 (wave w owns rows w*16..w*16+16), full N per block.
// B (wb) double-buffered in LDS via global_load_lds (32-wide K chunks);
// A (x, fp32) register-prefetched and converted to bf16 in-register.
// Epilogue: logits -> LDS, softmax over K per head + GLU gate -> cw (M,128).
// ---------------------------------------------------------------------------
__global__ __launch_bounds__(256) void logits_kernel(
    const float* __restrict__ x,       // (M, C) fp32
    const ushort* __restrict__ wb,     // (144, C) bf16
    const float* __restrict__ glu_b,   // (2H,) fp32
    float* __restrict__ cw)            // (M, 128) fp32
{
    __shared__ __align__(16) ushort Bs[2][144 * 32];  // 2 x 9216 B
    __shared__ float lsm[64][NLOG];                   // 36,864 B

    const int tid = threadIdx.x;
    const int wave = tid >> 6, lane = tid & 63;
    const int fr = lane & 15, q = lane >> 4;
    const int m0 = blockIdx.x * 64;
    const int mrow = m0 + wave * 16 + fr;

    floatx4 acc[9];
#pragma unroll
    for (int j = 0; j < 9; ++j) acc[j] = (floatx4){0.f, 0.f, 0.f, 0.f};

    const float* arow = x + (size_t)mrow * C_DIM + q * 8;

    // stage B chunk 0 (144 rows x 32 cols bf16 = 576 x 16B)
    for (int i = tid; i < 576; i += 256) {
        int r = i >> 2, ch = i & 3;
        __builtin_amdgcn_global_load_lds(
            (const __attribute__((address_space(1))) void*)(wb + (size_t)r * C_DIM + ch * 8),
            (__attribute__((address_space(3))) void*)(&Bs[0][0] + i * 8), 16, 0, 0);
    }
    float4 a0 = *(const float4*)(arow);
    float4 a1 = *(const float4*)(arow + 4);
    __syncthreads();

    for (int kc = 0; kc < 32; ++kc) {
        const int buf = kc & 1;
        if (kc < 31) {                        // stage next B chunk into other buffer
            const ushort* wsrc = wb + (kc + 1) * 32;
            for (int i = tid; i < 576; i += 256) {
                int r = i >> 2, ch = i & 3;
                __builtin_amdgcn_global_load_lds(
                    (const __attribute__((address_space(1))) void*)(wsrc + (size_t)r * C_DIM + ch * 8),
                    (__attribute__((address_space(3))) void*)(&Bs[buf ^ 1][0] + i * 8), 16, 0, 0);
            }
        }
        short8 a;
        a[0] = (short)f2bf(a0.x); a[1] = (short)f2bf(a0.y);
        a[2] = (short)f2bf(a0.z); a[3] = (short)f2bf(a0.w);
        a[4] = (short)f2bf(a1.x); a[5] = (short)f2bf(a1.y);
        a[6] = (short)f2bf(a1.z); a[7] = (short)f2bf(a1.w);
        if (kc < 31) {                        // prefetch next A
            a0 = *(const float4*)(arow + (kc + 1) * 32);
            a1 = *(const float4*)(arow + (kc + 1) * 32 + 4);
        }
#pragma unroll
        for (int j = 0; j < 9; ++j) {
            // conflict-free: lane (q,fr) -> 16B slot fr*4+q, contiguous 1 KB/wave
            short8 b = *(const short8*)(&Bs[buf][0] + ((j * 16 + fr) * 4 + q) * 8);
            acc[j] = __builtin_amdgcn_mfma_f32_16x16x32_bf16(a, b, acc[j], 0, 0, 0);
        }
        __syncthreads();
    }

    // ---- epilogue: logits -> LDS, then softmax + gate -> cw ----
#pragma unroll
    for (int j = 0; j < 9; ++j)
#pragma unroll
        for (int r = 0; r < 4; ++r)
            lsm[wave * 16 + q * 4 + r][j * 16 + fr] = acc[j][r];
    __syncthreads();

    {
        const int row = tid >> 2;             // [0,64)
        const int hbase = (tid & 3) * 4;      // 4 heads per thread
        float* crow = cw + (size_t)(m0 + row) * CW_STRIDE;
#pragma unroll
        for (int hh = 0; hh < 4; ++hh) {
            const int h = hbase + hh;
            float l[K_DIM];
            float mx = -1e30f;
#pragma unroll
            for (int k = 0; k < K_DIM; ++k) { l[k] = lsm[row][h * K_DIM + k]; mx = fmaxf(mx, l[k]); }
            float s = 0.f;
#pragma unroll
            for (int k = 0; k < K_DIM; ++k) { l[k] = __expf(l[k] - mx); s += l[k]; }
            float inv = 1.f / s;
#pragma unroll
            for (int k = 0; k < K_DIM; ++k) crow[h * K_DIM + k] = l[k] * inv;
            float ga = lsm[row][112 + 2 * h] + glu_b[2 * h];
            float gb = lsm[row][113 + 2 * h] + glu_b[2 * h + 1];
            crow[112 + h] = ga * (1.f / (1.f + __expf(-gb)));
        }
    }
}

// ---------------------------------------------------------------------------
// Kernel V: depthwise dynamic conv + gate. One wave per m-row; grid 4096
// blocks of 4 waves. XCD-swizzled so XCD k owns contiguous t-range (7-tap
// history L2-local). Lane L: channels [16L,16L+16), head = L>>2.
// ---------------------------------------------------------------------------
__global__ __launch_bounds__(256) void conv_kernel(
    const float* __restrict__ x,        // (M, C) fp32
    const float* __restrict__ cw,       // (M, 128) fp32
    const int* __restrict__ padding_l_, // scalar
    ushort* __restrict__ y)             // (M, C) bf16
{
    const int lb = (blockIdx.x & 7) * 512 + (blockIdx.x >> 3);  // XCD-contig t
    const int wave = threadIdx.x >> 6, lane = threadIdx.x & 63;
    const int m = lb * 4 + wave;
    const int t = m >> 3;
    const int pad = *padding_l_;
    const int h = lane >> 2;

    const float* crow = cw + (size_t)m * CW_STRIDE;
    float wt[K_DIM];
#pragma unroll
    for (int k = 0; k < K_DIM; ++k) wt[k] = crow[h * K_DIM + k];
    const float g = crow[112 + h];

    const int c0 = lane * 16;
    float av[16];
#pragma unroll
    for (int i = 0; i < 16; ++i) av[i] = 0.f;

#pragma unroll
    for (int k = 0; k < K_DIM; ++k) {
        int ts = t + k - pad;
        if (ts < 0 || ts >= T_DIM) continue;
        float wv = wt[k];
        const float4* xp = (const float4*)(x + ((size_t)m + 8 * (k - pad)) * C_DIM + c0);
        float4 u0 = xp[0], u1 = xp[1], u2 = xp[2], u3 = xp[3];
        av[0]  += wv * u0.x; av[1]  += wv * u0.y; av[2]  += wv * u0.z; av[3]  += wv * u0.w;
        av[4]  += wv * u1.x; av[5]  += wv * u1.y; av[6]  += wv * u1.z; av[7]  += wv * u1.w;
        av[8]  += wv * u2.x; av[9]  += wv * u2.y; av[10] += wv * u2.z; av[11] += wv * u2.w;
        av[12] += wv * u3.x; av[13] += wv * u3.y; av[14] += wv * u3.z; av[15] += wv * u3.w;
    }

    uint32_t o[8];
#pragma unroll
    for (int i = 0; i < 8; ++i)
        o[i] = (uint32_t)f2bf(av[2 * i] * g) | ((uint32_t)f2bf(av[2 * i + 1] * g) << 16);
    uint4* yr = (uint4*)(y + (size_t)m * C_DIM + c0);
    yr[0] = (uint4){o[0], o[1], o[2], o[3]};
    yr[1] = (uint4){o[4], o[5], o[6], o[7]};
}

// ---------------------------------------------------------------------------
// Kernel C: out[m,n] = sum_k y[m,k] * Wb[n,k] + out_b[n]  (bf16 MFMA, fp32 out)
// 128x128 tile, BK=64, 2-phase double-buffered global_load_lds pipeline:
// stage k+1 BEFORE compute k, counted s_waitcnt vmcnt(8) (never 0 in loop),
// raw s_barrier (no full drain). XOR chunk swizzle for conflict-free
// ds_read_b128. Epilogue: acc -> LDS (reuse 64KB staging as 128x128 fp32),
// read back row-major, floatx4 nontemporal stores (full cache lines, no RMW).
// Dispatch mapping: round-2 natural order (measured fastest).
// ---------------------------------------------------------------------------
__global__ __launch_bounds__(256) void out_gemm(
    const ushort* __restrict__ y,     // (M, C) bf16
    const ushort* __restrict__ Wb,    // (C, C) bf16
    const float* __restrict__ bias,   // (C,) fp32
    float* __restrict__ out)          // (M, C) fp32
{
    // [buf][A=0/B=1][128*64] bf16 = 65536 B total; aliased as 128x128 fp32
    // for the epilogue transpose.
    __shared__ __align__(16) ushort SM[2][2][128 * 64];

    const int bn = blockIdx.x & 7;       // N/128 = 8
    const int bm = blockIdx.x >> 3;      // M/128 = 128
    const int m0 = bm * 128, n0 = bn * 128;
    const int tid = threadIdx.x;
    const int lane = tid & 63, wave = tid >> 6;
    const int wm = (wave >> 1) * 64, wn = (wave & 1) * 64;
    const int fr = lane & 15, q = lane >> 4;

    floatx4 acc[4][4];
#pragma unroll
    for (int i = 0; i < 4; ++i)
#pragma unroll
        for (int j = 0; j < 4; ++j) acc[i][j] = (floatx4){0.f, 0.f, 0.f, 0.f};

    // stage one 128x64 A-tile + B-tile into SM[buf] (8 loads/thread)
    auto stage = [&](int buf, int k0) {
#pragma unroll
        for (int j = 0; j < 4; ++j) {
            int idx = j * 256 + tid;          // LDS 16B-slot index [0,1024)
            int r = idx >> 3, cl = idx & 7;   // row, LDS chunk
            int ch = cl ^ (r & 7);            // which global chunk lands here
            __builtin_amdgcn_global_load_lds(
                (const __attribute__((address_space(1))) void*)(y + (size_t)(m0 + r) * C_DIM + k0 + ch * 8),
                (__attribute__((address_space(3))) void*)(&SM[buf][0][0] + idx * 8), 16, 0, 0);
            __builtin_amdgcn_global_load_lds(
                (const __attribute__((address_space(1))) void*)(Wb + (size_t)(n0 + r) * C_DIM + k0 + ch * 8),
                (__attribute__((address_space(3))) void*)(&SM[buf][1][0] + idx * 8), 16, 0, 0);
        }
    };

    stage(0, 0);                              // prologue

#pragma unroll 2
    for (int kt = 0; kt < 16; ++kt) {
        const int buf = kt & 1;
        if (kt < 15) {
            stage(buf ^ 1, (kt + 1) * 64);    // issue next tile's loads first
            asm volatile("s_waitcnt vmcnt(8)" ::: "memory");  // oldest 8 (this buf) done
        } else {
            asm volatile("s_waitcnt vmcnt(0)" ::: "memory");
        }
        __builtin_amdgcn_s_barrier();         // all waves' stages of buf landed
        asm volatile("" ::: "memory");

        const ushort* Ab = &SM[buf][0][0];
        const ushort* Bb = &SM[buf][1][0];
#pragma unroll
        for (int s = 0; s < 64; s += 32) {
            const int cbase = (s >> 3) + q;
            short8 a[4], b[4];
#pragma unroll
            for (int i = 0; i < 4; ++i) {
                int r = wm + i * 16 + fr;
                a[i] = *(const short8*)(Ab + r * 64 + ((cbase ^ (r & 7)) * 8));
            }
#pragma unroll
            for (int j = 0; j < 4; ++j) {
                int r = wn + j * 16 + fr;
                b[j] = *(const short8*)(Bb + r * 64 + ((cbase ^ (r & 7)) * 8));
            }
#pragma unroll
            for (int i = 0; i < 4; ++i)
#pragma unroll
                for (int j = 0; j < 4; ++j)
                    acc[i][j] = __builtin_amdgcn_mfma_f32_16x16x32_bf16(a[i], b[j], acc[i][j], 0, 0, 0);
        }

        asm volatile("" ::: "memory");
        __builtin_amdgcn_s_barrier();         // all waves done reading buf
        asm volatile("" ::: "memory");
    }

    // ---- epilogue: acc -> LDS (128x128 fp32 = exactly 64 KB), transpose to
    // row-major floatx4 nontemporal stores ----
    float* Cs = (float*)&SM[0][0][0];
#pragma unroll
    for (int i = 0; i < 4; ++i)
#pragma unroll
        for (int j = 0; j < 4; ++j)
#pragma unroll
            for (int r = 0; r < 4; ++r)
                Cs[(wm + i * 16 + q * 4 + r) * 128 + (wn + j * 16 + fr)] = acc[i][j][r];
    __syncthreads();

    {
        const int c4 = (tid & 31) * 4;        // col [0,128) step 4, fixed per thread
        floatx4 bv = *(const floatx4*)(bias + n0 + c4);
#pragma unroll
        for (int rep = 0; rep < 16; ++rep) {
            int row = rep * 8 + (tid >> 5);   // [0,128)
            floatx4 v = *(const floatx4*)(Cs + row * 128 + c4);
            v = v + bv;
            __builtin_nontemporal_store(v, (floatx4*)(out + (size_t)(m0 + row) * C_DIM + n0 + c4));
        }
    }
}

// ---------------------------------------------------------------------------
extern "C" void kernel_launch(void* const* d_in, const int* in_sizes, int n_in,
                              void* d_out, int out_size, void* d_ws, size_t ws_size,
                              hipStream_t stream) {
    const float* x        = (const float*)d_in[0];
    const float* w_weight = (const float*)d_in[1];
    const float* glu_w    = (const float*)d_in[2];
    const float* glu_b    = (const float*)d_in[3];
    const float* out_w    = (const float*)d_in[4];
    const float* out_b    = (const float*)d_in[5];
    const int* padding_l  = (const int*)d_in[6];
    float* out = (float*)d_out;

    char* ws = (char*)d_ws;
    ushort* y  = (ushort*)ws;                          // M*C bf16   (33.5 MB)
    ushort* wb = y + (size_t)M_DIM * C_DIM;            // 144*C bf16 (0.3 MB)
    ushort* Wb = wb + S_WG;                            // C*C bf16   (2.1 MB)
    float* cwp = (float*)(Wb + S_O);                   // M*128 fp32 (8.4 MB)

    cvt_w_kernel<<<S_CVT / 4 / 256, 256, 0, stream>>>(w_weight, glu_w, out_w, wb, Wb);
    logits_kernel<<<M_DIM / 64, 256, 0, stream>>>(x, wb, glu_b, cwp);
    conv_kernel<<<M_DIM / 4, 256, 0, stream>>>(x, cwp, padding_l, y);
    out_gemm<<<(M_DIM / 128) * (C_DIM / 128), 256, 0, stream>>>(y, Wb, out_b, out);
}

// Round 4
// 221.499 us; speedup vs baseline: 1.0568x; 1.0568x over previous
//
#include <hip/hip_runtime.h>
#include <hip/hip_bf16.h>
#include <stdint.h>

// Problem constants (DynamicConv1dTBC): T=2048 B=8 C=1024 H=16 K=7 pad_l=6
#define T_DIM 2048
#define B_DIM 8
#define C_DIM 1024
#define H_DIM 16
#define K_DIM 7
#define M_DIM (T_DIM * B_DIM)   // 16384 rows (m = t*B + b)
#define NLOG 144                // H*K (112) + 2H (32) logit columns
#define CW_STRIDE 128           // compact conv-weights row: 112 wk + 16 gates

typedef __attribute__((ext_vector_type(8))) short short8;
typedef __attribute__((ext_vector_type(4))) float floatx4;

__device__ __forceinline__ ushort f2bf(float f) {
    __hip_bfloat16 h = __float2bfloat16(f);
    return *(ushort*)&h;
}

// ---------------------------------------------------------------------------
// Kernel W: fp32 -> bf16 downcast of weights: [w_weight;glu_w] -> wb (144x1024)
// and out_w -> Wb (1024x1024).
// ---------------------------------------------------------------------------
#define S_W  ((size_t)112 * C_DIM)
#define S_G  ((size_t)32 * C_DIM)
#define S_O  ((size_t)C_DIM * C_DIM)
#define S_WG (S_W + S_G)
#define S_CVT (S_WG + S_O)                  // 1,196,032 = 4*256*1168

__global__ __launch_bounds__(256) void cvt_w_kernel(
    const float* __restrict__ w_weight, const float* __restrict__ glu_w,
    const float* __restrict__ out_w,
    ushort* __restrict__ wb, ushort* __restrict__ Wb)
{
    size_t gid = ((size_t)blockIdx.x * 256 + threadIdx.x) * 4;
    const float* src; ushort* dst; size_t off;
    if (gid < S_W)            { src = w_weight; dst = wb;       off = gid; }
    else if (gid < S_WG)      { src = glu_w;    dst = wb + S_W; off = gid - S_W; }
    else                      { src = out_w;    dst = Wb;       off = gid - S_WG; }
    float4 v = *(const float4*)(src + off);
    ushort4 o; o.x = f2bf(v.x); o.y = f2bf(v.y); o.z = f2bf(v.z); o.w = f2bf(v.w);
    *(ushort4*)(dst + off) = o;
}

// ---------------------------------------------------------------------------
// Kernel L: logits GEMM (M=16384, N=144, K=1024) + softmax/gate epilogue.
// (unchanged from round 3 — measured < 53 us, not the current bottleneck)
// ---------------------------------------------------------------------------
__global__ __launch_bounds__(256) void logits_kernel(
    const float* __restrict__ x,       // (M, C) fp32
    const ushort* __restrict__ wb,     // (144, C) bf16
    const float* __restrict__ glu_b,   // (2H,) fp32
    float* __restrict__ cw)            // (M, 128) fp32
{
    __shared__ __align__(16) ushort Bs[2][144 * 32];  // 2 x 9216 B
    __shared__ float lsm[64][NLOG];                   // 36,864 B

    const int tid = threadIdx.x;
    const int wave = tid >> 6, lane = tid & 63;
    const int fr = lane & 15, q = lane >> 4;
    const int m0 = blockIdx.x * 64;
    const int mrow = m0 + wave * 16 + fr;

    floatx4 acc[9];
#pragma unroll
    for (int j = 0; j < 9; ++j) acc[j] = (floatx4){0.f, 0.f, 0.f, 0.f};

    const float* arow = x + (size_t)mrow * C_DIM + q * 8;

    // stage B chunk 0 (144 rows x 32 cols bf16 = 576 x 16B)
    for (int i = tid; i < 576; i += 256) {
        int r = i >> 2, ch = i & 3;
        __builtin_amdgcn_global_load_lds(
            (const __attribute__((address_space(1))) void*)(wb + (size_t)r * C_DIM + ch * 8),
            (__attribute__((address_space(3))) void*)(&Bs[0][0] + i * 8), 16, 0, 0);
    }
    float4 a0 = *(const float4*)(arow);
    float4 a1 = *(const float4*)(arow + 4);
    __syncthreads();

    for (int kc = 0; kc < 32; ++kc) {
        const int buf = kc & 1;
        if (kc < 31) {                        // stage next B chunk into other buffer
            const ushort* wsrc = wb + (kc + 1) * 32;
            for (int i = tid; i < 576; i += 256) {
                int r = i >> 2, ch = i & 3;
                __builtin_amdgcn_global_load_lds(
                    (const __attribute__((address_space(1))) void*)(wsrc + (size_t)r * C_DIM + ch * 8),
                    (__attribute__((address_space(3))) void*)(&Bs[buf ^ 1][0] + i * 8), 16, 0, 0);
            }
        }
        short8 a;
        a[0] = (short)f2bf(a0.x); a[1] = (short)f2bf(a0.y);
        a[2] = (short)f2bf(a0.z); a[3] = (short)f2bf(a0.w);
        a[4] = (short)f2bf(a1.x); a[5] = (short)f2bf(a1.y);
        a[6] = (short)f2bf(a1.z); a[7] = (short)f2bf(a1.w);
        if (kc < 31) {                        // prefetch next A
            a0 = *(const float4*)(arow + (kc + 1) * 32);
            a1 = *(const float4*)(arow + (kc + 1) * 32 + 4);
        }
#pragma unroll
        for (int j = 0; j < 9; ++j) {
            // conflict-free: lane (q,fr) -> 16B slot fr*4+q, contiguous 1 KB/wave
            short8 b = *(const short8*)(&Bs[buf][0] + ((j * 16 + fr) * 4 + q) * 8);
            acc[j] = __builtin_amdgcn_mfma_f32_16x16x32_bf16(a, b, acc[j], 0, 0, 0);
        }
        __syncthreads();
    }

    // ---- epilogue: logits -> LDS, then softmax + gate -> cw ----
#pragma unroll
    for (int j = 0; j < 9; ++j)
#pragma unroll
        for (int r = 0; r < 4; ++r)
            lsm[wave * 16 + q * 4 + r][j * 16 + fr] = acc[j][r];
    __syncthreads();

    {
        const int row = tid >> 2;             // [0,64)
        const int hbase = (tid & 3) * 4;      // 4 heads per thread
        float* crow = cw + (size_t)(m0 + row) * CW_STRIDE;
#pragma unroll
        for (int hh = 0; hh < 4; ++hh) {
            const int h = hbase + hh;
            float l[K_DIM];
            float mx = -1e30f;
#pragma unroll
            for (int k = 0; k < K_DIM; ++k) { l[k] = lsm[row][h * K_DIM + k]; mx = fmaxf(mx, l[k]); }
            float s = 0.f;
#pragma unroll
            for (int k = 0; k < K_DIM; ++k) { l[k] = __expf(l[k] - mx); s += l[k]; }
            float inv = 1.f / s;
#pragma unroll
            for (int k = 0; k < K_DIM; ++k) crow[h * K_DIM + k] = l[k] * inv;
            float ga = lsm[row][112 + 2 * h] + glu_b[2 * h];
            float gb = lsm[row][113 + 2 * h] + glu_b[2 * h + 1];
            crow[112 + h] = ga * (1.f / (1.f + __expf(-gb)));
        }
    }
}

// ---------------------------------------------------------------------------
// Kernel V: depthwise dynamic conv + gate. (unchanged from round 3)
// ---------------------------------------------------------------------------
__global__ __launch_bounds__(256) void conv_kernel(
    const float* __restrict__ x,        // (M, C) fp32
    const float* __restrict__ cw,       // (M, 128) fp32
    const int* __restrict__ padding_l_, // scalar
    ushort* __restrict__ y)             // (M, C) bf16
{
    const int lb = (blockIdx.x & 7) * 512 + (blockIdx.x >> 3);  // XCD-contig t
    const int wave = threadIdx.x >> 6, lane = threadIdx.x & 63;
    const int m = lb * 4 + wave;
    const int t = m >> 3;
    const int pad = *padding_l_;
    const int h = lane >> 2;

    const float* crow = cw + (size_t)m * CW_STRIDE;
    float wt[K_DIM];
#pragma unroll
    for (int k = 0; k < K_DIM; ++k) wt[k] = crow[h * K_DIM + k];
    const float g = crow[112 + h];

    const int c0 = lane * 16;
    float av[16];
#pragma unroll
    for (int i = 0; i < 16; ++i) av[i] = 0.f;

#pragma unroll
    for (int k = 0; k < K_DIM; ++k) {
        int ts = t + k - pad;
        if (ts < 0 || ts >= T_DIM) continue;
        float wv = wt[k];
        const float4* xp = (const float4*)(x + ((size_t)m + 8 * (k - pad)) * C_DIM + c0);
        float4 u0 = xp[0], u1 = xp[1], u2 = xp[2], u3 = xp[3];
        av[0]  += wv * u0.x; av[1]  += wv * u0.y; av[2]  += wv * u0.z; av[3]  += wv * u0.w;
        av[4]  += wv * u1.x; av[5]  += wv * u1.y; av[6]  += wv * u1.z; av[7]  += wv * u1.w;
        av[8]  += wv * u2.x; av[9]  += wv * u2.y; av[10] += wv * u2.z; av[11] += wv * u2.w;
        av[12] += wv * u3.x; av[13] += wv * u3.y; av[14] += wv * u3.z; av[15] += wv * u3.w;
    }

    uint32_t o[8];
#pragma unroll
    for (int i = 0; i < 8; ++i)
        o[i] = (uint32_t)f2bf(av[2 * i] * g) | ((uint32_t)f2bf(av[2 * i + 1] * g) << 16);
    uint4* yr = (uint4*)(y + (size_t)m * C_DIM + c0);
    yr[0] = (uint4){o[0], o[1], o[2], o[3]};
    yr[1] = (uint4){o[4], o[5], o[6], o[7]};
}

// ---------------------------------------------------------------------------
// Kernel C: out = y @ Wb^T + bias.  256x256 tile, 8 waves (512 thr), BK=32.
// TRIPLE-buffered LDS (96 KB), 2-K-step prefetch lead, counted
// s_waitcnt vmcnt(8) (never 0 in steady loop) so 2 future stages stay in
// flight across barriers (T4). setprio(1) around the 32-MFMA cluster (T5).
// Chunk-XOR swizzle ch^((r>>1)&3): each 8-lane octet of ds_read_b128 hits
// all 8 distinct 16B slot positions -> conflict-free.
// Grid 256 blocks = 1/CU; XCD-chunked swizzle so the 4 bn-blocks sharing a
// y panel live on one XCD (panel fetched ~once per XCD L2).
// ---------------------------------------------------------------------------
__global__ __launch_bounds__(512, 2) void out_gemm(
    const ushort* __restrict__ y,     // (M, C) bf16
    const ushort* __restrict__ Wb,    // (C, C) bf16
    const float* __restrict__ bias,   // (C,) fp32
    float* __restrict__ out)          // (M, C) fp32
{
    // [buf][A=0/B=1][256 rows * 32 cols bf16 = 16 KB] -> 3*2*16 = 96 KB
    __shared__ __align__(16) ushort SM[3][2][256 * 32];

    // XCD-chunk swizzle: hw block b -> orig tile id; each XCD (b&7) gets 32
    // consecutive tile ids = 8 full bm-groups (bn varies fastest within bm).
    const int orig = (blockIdx.x & 7) * 32 + (blockIdx.x >> 3);
    const int bm = orig >> 2;            // M/256 = 64
    const int bn = orig & 3;             // N/256 = 4
    const int m0 = bm * 256, n0 = bn * 256;
    const int tid = threadIdx.x;
    const int lane = tid & 63, wave = tid >> 6;
    const int wr = wave >> 2;            // 2 M-halves (128 rows each)
    const int wc = wave & 3;             // 4 N-quarters (64 cols each)
    const int fr = lane & 15, q = lane >> 4;

    floatx4 acc[8][4];
#pragma unroll
    for (int i = 0; i < 8; ++i)
#pragma unroll
        for (int j = 0; j < 4; ++j) acc[i][j] = (floatx4){0.f, 0.f, 0.f, 0.f};

    // stage one 256x32 A-tile + B-tile into SM[buf]; 4 loads/thread.
    // LDS dest linear in tid (wave-uniform base + lane*16: required by HW);
    // global source pre-swizzled so read-side XOR sees linear data.
    auto stage = [&](int buf, int k0) {
#pragma unroll
        for (int j = 0; j < 2; ++j) {
            int idx = j * 512 + tid;          // 16B slot index [0,1024)
            int r = idx >> 2, cl = idx & 3;   // row [0,256), LDS chunk [0,4)
            int ch = cl ^ ((r >> 1) & 3);     // which global chunk lands here
            __builtin_amdgcn_global_load_lds(
                (const __attribute__((address_space(1))) void*)(y + (size_t)(m0 + r) * C_DIM + k0 + ch * 8),
                (__attribute__((address_space(3))) void*)(&SM[buf][0][0] + idx * 8), 16, 0, 0);
            __builtin_amdgcn_global_load_lds(
                (const __attribute__((address_space(1))) void*)(Wb + (size_t)(n0 + r) * C_DIM + k0 + ch * 8),
                (__attribute__((address_space(3))) void*)(&SM[buf][1][0] + idx * 8), 16, 0, 0);
        }
    };

    stage(0, 0);                              // prologue: 2 K-steps ahead
    stage(1, 32);

    int cur = 0;
    for (int kt = 0; kt < 32; ++kt) {
        if (kt + 2 < 32) {
            int stg = cur + 2; if (stg >= 3) stg -= 3;
            stage(stg, (kt + 2) * 32);        // 12 loads in flight after this
        }
        // wait for stage(kt)'s 4 loads only; stages kt+1, kt+2 stay in flight
        if (kt < 30)       asm volatile("s_waitcnt vmcnt(8)" ::: "memory");
        else if (kt == 30) asm volatile("s_waitcnt vmcnt(4)" ::: "memory");
        else               asm volatile("s_waitcnt vmcnt(0)" ::: "memory");
        __builtin_amdgcn_s_barrier();         // all waves' stage(kt) landed
        asm volatile("" ::: "memory");

        const ushort* Ab = &SM[cur][0][0];
        const ushort* Bb = &SM[cur][1][0];
        short8 a[8], b[4];
#pragma unroll
        for (int mf = 0; mf < 8; ++mf) {
            int r = wr * 128 + mf * 16 + fr;
            a[mf] = *(const short8*)(Ab + r * 32 + ((q ^ ((r >> 1) & 3)) * 8));
        }
#pragma unroll
        for (int nf = 0; nf < 4; ++nf) {
            int r = wc * 64 + nf * 16 + fr;
            b[nf] = *(const short8*)(Bb + r * 32 + ((q ^ ((r >> 1) & 3)) * 8));
        }
        __builtin_amdgcn_s_setprio(1);
#pragma unroll
        for (int mf = 0; mf < 8; ++mf)
#pragma unroll
            for (int nf = 0; nf < 4; ++nf)
                acc[mf][nf] = __builtin_amdgcn_mfma_f32_16x16x32_bf16(a[mf], b[nf], acc[mf][nf], 0, 0, 0);
        __builtin_amdgcn_s_setprio(0);

        asm volatile("" ::: "memory");
        __builtin_amdgcn_s_barrier();         // all waves done reading cur
        asm volatile("" ::: "memory");
        cur = (cur == 2) ? 0 : cur + 1;
    }

    // ---- epilogue: direct stores (wave tile 128x64) ----
#pragma unroll
    for (int nf = 0; nf < 4; ++nf) {
        int n = n0 + wc * 64 + nf * 16 + fr;
        float bv = bias[n];
#pragma unroll
        for (int mf = 0; mf < 8; ++mf) {
#pragma unroll
            for (int r = 0; r < 4; ++r) {
                int m = m0 + wr * 128 + mf * 16 + q * 4 + r;
                out[(size_t)m * C_DIM + n] = acc[mf][nf][r] + bv;
            }
        }
    }
}

// ---------------------------------------------------------------------------
extern "C" void kernel_launch(void* const* d_in, const int* in_sizes, int n_in,
                              void* d_out, int out_size, void* d_ws, size_t ws_size,
                              hipStream_t stream) {
    const float* x        = (const float*)d_in[0];
    const float* w_weight = (const float*)d_in[1];
    const float* glu_w    = (const float*)d_in[2];
    const float* glu_b    = (const float*)d_in[3];
    const float* out_w    = (const float*)d_in[4];
    const float* out_b    = (const float*)d_in[5];
    const int* padding_l  = (const int*)d_in[6];
    float* out = (float*)d_out;

    char* ws = (char*)d_ws;
    ushort* y  = (ushort*)ws;                          // M*C bf16   (33.5 MB)
    ushort* wb = y + (size_t)M_DIM * C_DIM;            // 144*C bf16 (0.3 MB)
    ushort* Wb = wb + S_WG;                            // C*C bf16   (2.1 MB)
    float* cwp = (float*)(Wb + S_O);                   // M*128 fp32 (8.4 MB)

    cvt_w_kernel<<<S_CVT / 4 / 256, 256, 0, stream>>>(w_weight, glu_w, out_w, wb, Wb);
    logits_kernel<<<M_DIM / 64, 256, 0, stream>>>(x, wb, glu_b, cwp);
    conv_kernel<<<M_DIM / 4, 256, 0, stream>>>(x, cwp, padding_l, y);
    out_gemm<<<(M_DIM / 256) * (C_DIM / 256), 512, 0, stream>>>(y, Wb, out_b, out);
}

// Round 5
// 216.546 us; speedup vs baseline: 1.0810x; 1.0229x over previous
//
#include <hip/hip_runtime.h>
#include <hip/hip_bf16.h>
#include <stdint.h>

// Problem constants (DynamicConv1dTBC): T=2048 B=8 C=1024 H=16 K=7 pad_l=6
#define T_DIM 2048
#define B_DIM 8
#define C_DIM 1024
#define H_DIM 16
#define K_DIM 7
#define M_DIM (T_DIM * B_DIM)   // 16384 rows (m = t*B + b)
#define NLOG 144                // H*K (112) + 2H (32) logit columns
#define CW_STRIDE 128           // compact conv-weights row: 112 wk + 16 gates

typedef __attribute__((ext_vector_type(8))) short short8;
typedef __attribute__((ext_vector_type(4))) float floatx4;

__device__ __forceinline__ ushort f2bf(float f) {
    __hip_bfloat16 h = __float2bfloat16(f);
    return *(ushort*)&h;
}

// ---------------------------------------------------------------------------
// Kernel W: fp32 -> bf16 downcast of weights: [w_weight;glu_w] -> wb (144x1024)
// and out_w -> Wb (1024x1024).
// ---------------------------------------------------------------------------
#define S_W  ((size_t)112 * C_DIM)
#define S_G  ((size_t)32 * C_DIM)
#define S_O  ((size_t)C_DIM * C_DIM)
#define S_WG (S_W + S_G)
#define S_CVT (S_WG + S_O)                  // 1,196,032 = 4*256*1168

__global__ __launch_bounds__(256) void cvt_w_kernel(
    const float* __restrict__ w_weight, const float* __restrict__ glu_w,
    const float* __restrict__ out_w,
    ushort* __restrict__ wb, ushort* __restrict__ Wb)
{
    size_t gid = ((size_t)blockIdx.x * 256 + threadIdx.x) * 4;
    const float* src; ushort* dst; size_t off;
    if (gid < S_W)            { src = w_weight; dst = wb;       off = gid; }
    else if (gid < S_WG)      { src = glu_w;    dst = wb + S_W; off = gid - S_W; }
    else                      { src = out_w;    dst = Wb;       off = gid - S_WG; }
    float4 v = *(const float4*)(src + off);
    ushort4 o; o.x = f2bf(v.x); o.y = f2bf(v.y); o.z = f2bf(v.z); o.w = f2bf(v.w);
    *(ushort4*)(dst + off) = o;
}

// ---------------------------------------------------------------------------
// Kernel L: logits GEMM (M=16384, N=144, K=1024) + softmax/gate epilogue.
// (unchanged — not the current bottleneck)
// ---------------------------------------------------------------------------
__global__ __launch_bounds__(256) void logits_kernel(
    const float* __restrict__ x,       // (M, C) fp32
    const ushort* __restrict__ wb,     // (144, C) bf16
    const float* __restrict__ glu_b,   // (2H,) fp32
    float* __restrict__ cw)            // (M, 128) fp32
{
    __shared__ __align__(16) ushort Bs[2][144 * 32];  // 2 x 9216 B
    __shared__ float lsm[64][NLOG];                   // 36,864 B

    const int tid = threadIdx.x;
    const int wave = tid >> 6, lane = tid & 63;
    const int fr = lane & 15, q = lane >> 4;
    const int m0 = blockIdx.x * 64;
    const int mrow = m0 + wave * 16 + fr;

    floatx4 acc[9];
#pragma unroll
    for (int j = 0; j < 9; ++j) acc[j] = (floatx4){0.f, 0.f, 0.f, 0.f};

    const float* arow = x + (size_t)mrow * C_DIM + q * 8;

    // stage B chunk 0 (144 rows x 32 cols bf16 = 576 x 16B)
    for (int i = tid; i < 576; i += 256) {
        int r = i >> 2, ch = i & 3;
        __builtin_amdgcn_global_load_lds(
            (const __attribute__((address_space(1))) void*)(wb + (size_t)r * C_DIM + ch * 8),
            (__attribute__((address_space(3))) void*)(&Bs[0][0] + i * 8), 16, 0, 0);
    }
    float4 a0 = *(const float4*)(arow);
    float4 a1 = *(const float4*)(arow + 4);
    __syncthreads();

    for (int kc = 0; kc < 32; ++kc) {
        const int buf = kc & 1;
        if (kc < 31) {                        // stage next B chunk into other buffer
            const ushort* wsrc = wb + (kc + 1) * 32;
            for (int i = tid; i < 576; i += 256) {
                int r = i >> 2, ch = i & 3;
                __builtin_amdgcn_global_load_lds(
                    (const __attribute__((address_space(1))) void*)(wsrc + (size_t)r * C_DIM + ch * 8),
                    (__attribute__((address_space(3))) void*)(&Bs[buf ^ 1][0] + i * 8), 16, 0, 0);
            }
        }
        short8 a;
        a[0] = (short)f2bf(a0.x); a[1] = (short)f2bf(a0.y);
        a[2] = (short)f2bf(a0.z); a[3] = (short)f2bf(a0.w);
        a[4] = (short)f2bf(a1.x); a[5] = (short)f2bf(a1.y);
        a[6] = (short)f2bf(a1.z); a[7] = (short)f2bf(a1.w);
        if (kc < 31) {                        // prefetch next A
            a0 = *(const float4*)(arow + (kc + 1) * 32);
            a1 = *(const float4*)(arow + (kc + 1) * 32 + 4);
        }
#pragma unroll
        for (int j = 0; j < 9; ++j) {
            // conflict-free: lane (q,fr) -> 16B slot fr*4+q, contiguous 1 KB/wave
            short8 b = *(const short8*)(&Bs[buf][0] + ((j * 16 + fr) * 4 + q) * 8);
            acc[j] = __builtin_amdgcn_mfma_f32_16x16x32_bf16(a, b, acc[j], 0, 0, 0);
        }
        __syncthreads();
    }

    // ---- epilogue: logits -> LDS, then softmax + gate -> cw ----
#pragma unroll
    for (int j = 0; j < 9; ++j)
#pragma unroll
        for (int r = 0; r < 4; ++r)
            lsm[wave * 16 + q * 4 + r][j * 16 + fr] = acc[j][r];
    __syncthreads();

    {
        const int row = tid >> 2;             // [0,64)
        const int hbase = (tid & 3) * 4;      // 4 heads per thread
        float* crow = cw + (size_t)(m0 + row) * CW_STRIDE;
#pragma unroll
        for (int hh = 0; hh < 4; ++hh) {
            const int h = hbase + hh;
            float l[K_DIM];
            float mx = -1e30f;
#pragma unroll
            for (int k = 0; k < K_DIM; ++k) { l[k] = lsm[row][h * K_DIM + k]; mx = fmaxf(mx, l[k]); }
            float s = 0.f;
#pragma unroll
            for (int k = 0; k < K_DIM; ++k) { l[k] = __expf(l[k] - mx); s += l[k]; }
            float inv = 1.f / s;
#pragma unroll
            for (int k = 0; k < K_DIM; ++k) crow[h * K_DIM + k] = l[k] * inv;
            float ga = lsm[row][112 + 2 * h] + glu_b[2 * h];
            float gb = lsm[row][113 + 2 * h] + glu_b[2 * h + 1];
            crow[112 + h] = ga * (1.f / (1.f + __expf(-gb)));
        }
    }
}

// ---------------------------------------------------------------------------
// Kernel V: depthwise dynamic conv + gate. (unchanged)
// ---------------------------------------------------------------------------
__global__ __launch_bounds__(256) void conv_kernel(
    const float* __restrict__ x,        // (M, C) fp32
    const float* __restrict__ cw,       // (M, 128) fp32
    const int* __restrict__ padding_l_, // scalar
    ushort* __restrict__ y)             // (M, C) bf16
{
    const int lb = (blockIdx.x & 7) * 512 + (blockIdx.x >> 3);  // XCD-contig t
    const int wave = threadIdx.x >> 6, lane = threadIdx.x & 63;
    const int m = lb * 4 + wave;
    const int t = m >> 3;
    const int pad = *padding_l_;
    const int h = lane >> 2;

    const float* crow = cw + (size_t)m * CW_STRIDE;
    float wt[K_DIM];
#pragma unroll
    for (int k = 0; k < K_DIM; ++k) wt[k] = crow[h * K_DIM + k];
    const float g = crow[112 + h];

    const int c0 = lane * 16;
    float av[16];
#pragma unroll
    for (int i = 0; i < 16; ++i) av[i] = 0.f;

#pragma unroll
    for (int k = 0; k < K_DIM; ++k) {
        int ts = t + k - pad;
        if (ts < 0 || ts >= T_DIM) continue;
        float wv = wt[k];
        const float4* xp = (const float4*)(x + ((size_t)m + 8 * (k - pad)) * C_DIM + c0);
        float4 u0 = xp[0], u1 = xp[1], u2 = xp[2], u3 = xp[3];
        av[0]  += wv * u0.x; av[1]  += wv * u0.y; av[2]  += wv * u0.z; av[3]  += wv * u0.w;
        av[4]  += wv * u1.x; av[5]  += wv * u1.y; av[6]  += wv * u1.z; av[7]  += wv * u1.w;
        av[8]  += wv * u2.x; av[9]  += wv * u2.y; av[10] += wv * u2.z; av[11] += wv * u2.w;
        av[12] += wv * u3.x; av[13] += wv * u3.y; av[14] += wv * u3.z; av[15] += wv * u3.w;
    }

    uint32_t o[8];
#pragma unroll
    for (int i = 0; i < 8; ++i)
        o[i] = (uint32_t)f2bf(av[2 * i] * g) | ((uint32_t)f2bf(av[2 * i + 1] * g) << 16);
    uint4* yr = (uint4*)(y + (size_t)m * C_DIM + c0);
    yr[0] = (uint4){o[0], o[1], o[2], o[3]};
    yr[1] = (uint4){o[4], o[5], o[6], o[7]};
}

// ---------------------------------------------------------------------------
// Kernel C: out = y @ Wb^T + bias.  256x256 tile, 8 waves, BK=64, 4-phase
// rhythm (8-phase template, m201 port). Regions per buffer: A0=[rows 0-127],
// A1, B0, B1 (each 128x64 bf16 = 16 KB); 2 buffers = 128 KB LDS.
// Per tile t (buf = t&1), phases:
//  P1: dsr A(mf0-3)+B(nf0-1) | stage A0_{t+1}->buf^1 | bar | MFMA lo x lo | bar
//  P2: dsr B(nf2-3)          | stage A1_{t+1}->buf^1 | bar | MFMA lo x hi | bar
//  P3: dsr A(mf4-7)          | stage B0_{t+2}->buf   | bar | MFMA hi x lo | bar
//  P4:                       | stage B1_{t+2}->buf, vmcnt(4) | bar | hi x hi | bar
// Race-free: B regions of buf are last READ in P2 (two barriers before the
// P3/P4 overwrite); A regions last read in P3, overwritten at (t+1).P1.
// vmcnt(4) (2 half-tiles in flight) once per tile — never drained to 0 in
// steady state. MFMA clusters use disjoint acc quadrants -> no inter-phase
// acc dependency, matrix pipe stays fed across barriers. Granule XOR
// g^(r&7) (8 granules/128B row) -> conflict-free ds_read_b128.
// Grid 256 = 1/CU, XCD-chunked swizzle (kept: FETCH 133->24.6 MB measured).
// ---------------------------------------------------------------------------
__global__ __launch_bounds__(512, 2) void out_gemm(
    const ushort* __restrict__ y,     // (M, C) bf16
    const ushort* __restrict__ Wb,    // (C, C) bf16
    const float* __restrict__ bias,   // (C,) fp32
    float* __restrict__ out)          // (M, C) fp32
{
    // [buf][region: A0,A1,B0,B1][128 rows * 64 cols bf16] = 128 KB
    __shared__ __align__(16) ushort SM[2][4][128 * 64];

    const int orig = (blockIdx.x & 7) * 32 + (blockIdx.x >> 3);
    const int bm = orig >> 2;            // M/256 = 64
    const int bn = orig & 3;             // N/256 = 4
    const int m0 = bm * 256, n0 = bn * 256;
    const int tid = threadIdx.x;
    const int lane = tid & 63, wave = tid >> 6;
    const int wr = wave >> 2;            // M-half owner (A region = wr)
    const int wc = wave & 3;             // N-quarter (B region = wc>>1)
    const int fr = lane & 15, q = lane >> 4;
    // per-thread swizzled granule byte-offsets for the two K=32 slices
    const int g0 = ((q) ^ (fr & 7)) * 8;       // ushort offset, ks=0
    const int g1 = ((4 + q) ^ (fr & 7)) * 8;   // ks=1

    floatx4 acc[8][4];
#pragma unroll
    for (int i = 0; i < 8; ++i)
#pragma unroll
        for (int j = 0; j < 4; ++j) acc[i][j] = (floatx4){0.f, 0.f, 0.f, 0.f};

    // stage one 128x64 region: mat 0=A(y rows m0+), 1=B(Wb rows n0+)
    auto stageH = [&](int buf, int mat, int half, int k0) {
        const ushort* src = mat ? Wb : y;
        const int row0 = (mat ? n0 : m0) + half * 128;
        ushort* dst = &SM[buf][mat * 2 + half][0];
#pragma unroll
        for (int j = 0; j < 2; ++j) {
            int idx = j * 512 + tid;          // 16B granule slot [0,1024)
            int r = idx >> 3, gl = idx & 7;
            int gs = gl ^ (r & 7);            // pre-swizzled global source
            __builtin_amdgcn_global_load_lds(
                (const __attribute__((address_space(1))) void*)(src + (size_t)(row0 + r) * C_DIM + k0 + gs * 8),
                (__attribute__((address_space(3))) void*)(dst + idx * 8), 16, 0, 0);
        }
    };

    // prologue: tile0 complete + B halves of tile1 (6 regions, 12 loads/thr)
    stageH(0, 0, 0, 0);  stageH(0, 0, 1, 0);    // A0_0 A1_0
    stageH(0, 1, 0, 0);  stageH(0, 1, 1, 0);    // B0_0 B1_0
    stageH(1, 1, 0, 64); stageH(1, 1, 1, 64);   // B0_1 B1_1
    asm volatile("s_waitcnt vmcnt(4)" ::: "memory");  // tile0 landed; B_1 in flight
    __builtin_amdgcn_s_barrier();
    asm volatile("" ::: "memory");

    short8 a[4][2], b[4][2];
    for (int t = 0; t < 16; ++t) {
        const int buf = t & 1;
        const ushort* Ar = &SM[buf][wr][0];
        const ushort* Br = &SM[buf][2 + (wc >> 1)][0];
        const int brb = (wc & 1) * 64;

        // ---------------- P1 ----------------
#pragma unroll
        for (int mf = 0; mf < 4; ++mf) {
            int ro = (mf * 16 + fr) * 64;
            a[mf][0] = *(const short8*)(Ar + ro + g0);
            a[mf][1] = *(const short8*)(Ar + ro + g1);
        }
#pragma unroll
        for (int nf = 0; nf < 2; ++nf) {
            int ro = (brb + nf * 16 + fr) * 64;
            b[nf][0] = *(const short8*)(Br + ro + g0);
            b[nf][1] = *(const short8*)(Br + ro + g1);
        }
        if (t + 1 < 16) stageH(buf ^ 1, 0, 0, (t + 1) * 64);
        __builtin_amdgcn_s_barrier();
        asm volatile("s_waitcnt lgkmcnt(0)" ::: "memory");
        __builtin_amdgcn_s_setprio(1);
#pragma unroll
        for (int ks = 0; ks < 2; ++ks)
#pragma unroll
            for (int mf = 0; mf < 4; ++mf)
#pragma unroll
                for (int nf = 0; nf < 2; ++nf)
                    acc[mf][nf] = __builtin_amdgcn_mfma_f32_16x16x32_bf16(a[mf][ks], b[nf][ks], acc[mf][nf], 0, 0, 0);
        __builtin_amdgcn_s_setprio(0);
        asm volatile("" ::: "memory");
        __builtin_amdgcn_s_barrier();
        asm volatile("" ::: "memory");

        // ---------------- P2 ----------------
#pragma unroll
        for (int nf = 2; nf < 4; ++nf) {
            int ro = (brb + nf * 16 + fr) * 64;
            b[nf][0] = *(const short8*)(Br + ro + g0);
            b[nf][1] = *(const short8*)(Br + ro + g1);
        }
        if (t + 1 < 16) stageH(buf ^ 1, 0, 1, (t + 1) * 64);
        __builtin_amdgcn_s_barrier();
        asm volatile("s_waitcnt lgkmcnt(0)" ::: "memory");
        __builtin_amdgcn_s_setprio(1);
#pragma unroll
        for (int ks = 0; ks < 2; ++ks)
#pragma unroll
            for (int mf = 0; mf < 4; ++mf)
#pragma unroll
                for (int nf = 2; nf < 4; ++nf)
                    acc[mf][nf] = __builtin_amdgcn_mfma_f32_16x16x32_bf16(a[mf][ks], b[nf][ks], acc[mf][nf], 0, 0, 0);
        __builtin_amdgcn_s_setprio(0);
        asm volatile("" ::: "memory");
        __builtin_amdgcn_s_barrier();
        asm volatile("" ::: "memory");

        // ---------------- P3 ----------------
#pragma unroll
        for (int mf = 0; mf < 4; ++mf) {
            int ro = ((mf + 4) * 16 + fr) * 64;
            a[mf][0] = *(const short8*)(Ar + ro + g0);
            a[mf][1] = *(const short8*)(Ar + ro + g1);
        }
        if (t + 2 < 16) stageH(buf, 1, 0, (t + 2) * 64);
        __builtin_amdgcn_s_barrier();
        asm volatile("s_waitcnt lgkmcnt(0)" ::: "memory");
        __builtin_amdgcn_s_setprio(1);
#pragma unroll
        for (int ks = 0; ks < 2; ++ks)
#pragma unroll
            for (int mf = 0; mf < 4; ++mf)
#pragma unroll
                for (int nf = 0; nf < 2; ++nf)
                    acc[mf + 4][nf] = __builtin_amdgcn_mfma_f32_16x16x32_bf16(a[mf][ks], b[nf][ks], acc[mf + 4][nf], 0, 0, 0);
        __builtin_amdgcn_s_setprio(0);
        asm volatile("" ::: "memory");
        __builtin_amdgcn_s_barrier();
        asm volatile("" ::: "memory");

        // ---------------- P4 ----------------
        if (t + 2 < 16) stageH(buf, 1, 1, (t + 2) * 64);
        if (t < 14)       { asm volatile("s_waitcnt vmcnt(4)" ::: "memory"); }
        else if (t == 14) { asm volatile("s_waitcnt vmcnt(0)" ::: "memory"); }
        __builtin_amdgcn_s_barrier();
        asm volatile("" ::: "memory");
        __builtin_amdgcn_s_setprio(1);
#pragma unroll
        for (int ks = 0; ks < 2; ++ks)
#pragma unroll
            for (int mf = 0; mf < 4; ++mf)
#pragma unroll
                for (int nf = 2; nf < 4; ++nf)
                    acc[mf + 4][nf] = __builtin_amdgcn_mfma_f32_16x16x32_bf16(a[mf][ks], b[nf][ks], acc[mf + 4][nf], 0, 0, 0);
        __builtin_amdgcn_s_setprio(0);
        asm volatile("" ::: "memory");
        __builtin_amdgcn_s_barrier();
        asm volatile("" ::: "memory");
    }

    // ---- epilogue: direct stores (wave tile 128x64; same mapping as r4) ----
#pragma unroll
    for (int nf = 0; nf < 4; ++nf) {
        int n = n0 + wc * 64 + nf * 16 + fr;
        float bv = bias[n];
#pragma unroll
        for (int mf = 0; mf < 8; ++mf) {
#pragma unroll
            for (int r = 0; r < 4; ++r) {
                int m = m0 + wr * 128 + mf * 16 + q * 4 + r;
                out[(size_t)m * C_DIM + n] = acc[mf][nf][r] + bv;
            }
        }
    }
}

// ---------------------------------------------------------------------------
extern "C" void kernel_launch(void* const* d_in, const int* in_sizes, int n_in,
                              void* d_out, int out_size, void* d_ws, size_t ws_size,
                              hipStream_t stream) {
    const float* x        = (const float*)d_in[0];
    const float* w_weight = (const float*)d_in[1];
    const float* glu_w    = (const float*)d_in[2];
    const float* glu_b    = (const float*)d_in[3];
    const float* out_w    = (const float*)d_in[4];
    const float* out_b    = (const float*)d_in[5];
    const int* padding_l  = (const int*)d_in[6];
    float* out = (float*)d_out;

    char* ws = (char*)d_ws;
    ushort* y  = (ushort*)ws;                          // M*C bf16   (33.5 MB)
    ushort* wb = y + (size_t)M_DIM * C_DIM;            // 144*C bf16 (0.3 MB)
    ushort* Wb = wb + S_WG;                            // C*C bf16   (2.1 MB)
    float* cwp = (float*)(Wb + S_O);                   // M*128 fp32 (8.4 MB)

    cvt_w_kernel<<<S_CVT / 4 / 256, 256, 0, stream>>>(w_weight, glu_w, out_w, wb, Wb);
    logits_kernel<<<M_DIM / 64, 256, 0, stream>>>(x, wb, glu_b, cwp);
    conv_kernel<<<M_DIM / 4, 256, 0, stream>>>(x, cwp, padding_l, y);
    out_gemm<<<(M_DIM / 256) * (C_DIM / 256), 512, 0, stream>>>(y, Wb, out_b, out);
}